// Round 4
// baseline (198.911 us; speedup 1.0000x reference)
//
#include <hip/hip_runtime.h>

namespace {
constexpr int IW = 512;
constexpr int IH = 512;
constexpr int ID = 64;
constexpr int PS = IH * IW;                      // plane stride (floats)
constexpr float W_Z  = 0.5f;                     // CONTIZ^2
constexpr float W_XY = 2.0f;
constexpr float W_XZ = 1.41421356237309515f;     // 2*CONTIZ = sqrt(2)

constexpr int TPB    = 256;
constexpr int NSEG   = 4;
constexpr int DSEG   = ID / NSEG;                // 16 d-steps per segment
constexpr int BLOCKS = 2 * NSEG * IH * (IW / 4) / TPB;   // 2048 = 8 blocks/CU exactly
}

__device__ __forceinline__ float4 ld4(const float* p) { return *(const float4*)p; }

__global__ __launch_bounds__(TPB, 8) void HessianReg_kernel(const float* __restrict__ img,
                                                            float* __restrict__ out) {
    // XCD swizzle: physical blocks round-robin the 8 XCDs (b%8); remap so each
    // XCD owns 256 consecutive logical blocks = one full (n,seg) slab of 512
    // rows -> all y-neighbor rows are XCD-L2-local.
    const int lblk  = (blockIdx.x & 7) * (BLOCKS / 8) + (blockIdx.x >> 3);
    const int t     = lblk * TPB + threadIdx.x;
    const int chunk = t & 127;          // float4 index within row
    const int r     = t >> 7;
    const int h     = r & (IH - 1);
    const int q     = r >> 9;           // [0,8): one slab per XCD
    const int seg   = q & 3;
    const int n     = q >> 2;
    const int d0    = seg * DSEG;
    const int w0    = chunk << 2;

    const bool hasW = (w0 < IW - 4);    // per-lane (false only for chunk 127)
    const bool hy2  = (h < IH - 1);     // wave-uniform
    const bool hy3  = (h < IH - 2);     // wave-uniform

    const float* p = img + ((size_t)((n * ID + d0) * IH + h)) * IW + w0;

    const float4 Z4 = make_float4(0.f, 0.f, 0.f, 0.f);

    // Rolling state (plane-relative): A=(d,h) B=(d,h+1) E=(d+1,h)
    // Working set for current step: C=(d,h+2) G=(d+1,h+1) F=(d+2,h)
    // Tails: a4,a5=A[+4,+5]; b4=B[+4]; e4,e5=E[+4,+5]; g4=G[+4]; f4,f5=F[+4,+5]
    float4 A = ld4(p);
    float a4 = 0.f, a5 = 0.f;
    if (hasW) { a4 = p[4]; a5 = p[5]; }
    float4 B = Z4; float b4 = 0.f;
    if (hy2) { B = ld4(p + IW); if (hasW) b4 = p[IW + 4]; }
    float4 E = ld4(p + PS);             // d0+1 <= 49: always valid
    float e4 = 0.f, e5 = 0.f;
    if (hasW) { e4 = p[PS + 4]; e5 = p[PS + 5]; }
    float4 C = Z4;
    if (hy3) C = ld4(p + 2 * IW);
    float4 G = Z4; float g4 = 0.f;
    if (hy2) { G = ld4(p + PS + IW); if (hasW) g4 = p[PS + IW + 4]; }  // d0+1 <= 49
    float4 F = ld4(p + 2 * PS);         // d0+2 <= 50: always valid
    float f4 = 0.f, f5 = 0.f;
    if (hasW) { f4 = p[2 * PS + 4]; f5 = p[2 * PS + 5]; }

    float acc = 0.f;

    for (int dl = 0; dl < DSEG; ++dl) {
        const int d = d0 + dl;          // wave-uniform

        // ---- prefetch next step's fresh planes (full iteration of latency cover)
        float4 Cn = Z4, Gn = Z4, Fn = Z4;
        float g4n = 0.f, f4n = 0.f, f5n = 0.f;
        if (dl + 1 < DSEG) {            // uniform branch
            const float* pn = p + PS;
            if (hy3) Cn = ld4(pn + 2 * IW);                 // plane d+1, row h+2
            if (hy2 && d <= ID - 3) {                       // plane d+2 exists
                Gn = ld4(pn + PS + IW);                     // -> G@d+1 -> B@d+2
                if (hasW) g4n = pn[PS + IW + 4];
            }
            if (d <= ID - 4) {                              // plane d+3 exists
                Fn = ld4(pn + 2 * PS);                      // -> F@d+1 -> E@d+2 -> A@d+3
                if (hasW) { f4n = pn[2 * PS + 4]; f5n = pn[2 * PS + 5]; }
            }
        }

        const bool gz2 = (d < ID - 1);  // wave-uniform
        const bool gz3 = (d < ID - 2);

        // g_xx (weight 1)
        {
            float s = fabsf(A.x - 2.f * A.y + A.z) + fabsf(A.y - 2.f * A.z + A.w);
            if (hasW) s += fabsf(A.z - 2.f * A.w + a4) + fabsf(A.w - 2.f * a4 + a5);
            acc += s;
        }
        // g_yy (weight 1)
        if (hy3)
            acc += fabsf(A.x - 2.f * B.x + C.x) + fabsf(A.y - 2.f * B.y + C.y)
                 + fabsf(A.z - 2.f * B.z + C.z) + fabsf(A.w - 2.f * B.w + C.w);
        // g_zz (weight 0.5)
        if (gz3)
            acc += W_Z * (fabsf(A.x - 2.f * E.x + F.x) + fabsf(A.y - 2.f * E.y + F.y)
                        + fabsf(A.z - 2.f * E.z + F.z) + fabsf(A.w - 2.f * E.w + F.w));
        // g_xy (weight 2)
        if (hy2) {
            float s = fabsf(A.x - A.y - B.x + B.y) + fabsf(A.y - A.z - B.y + B.z)
                    + fabsf(A.z - A.w - B.z + B.w);
            if (hasW) s += fabsf(A.w - a4 - B.w + b4);
            acc += W_XY * s;
        }
        // g_xz (weight sqrt(2))
        if (gz2) {
            float s = fabsf(A.x - A.y - E.x + E.y) + fabsf(A.y - A.z - E.y + E.z)
                    + fabsf(A.z - A.w - E.z + E.w);
            if (hasW) s += fabsf(A.w - a4 - E.w + e4);
            acc += W_XZ * s;
        }
        // g_yz (weight sqrt(2))
        if (gz2 && hy2)
            acc += W_XZ * (fabsf(A.x - B.x - E.x + G.x) + fabsf(A.y - B.y - E.y + G.y)
                         + fabsf(A.z - B.z - E.z + G.z) + fabsf(A.w - B.w - E.w + G.w));

        // ---- roll z
        A = E; a4 = e4; a5 = e5;
        B = G; b4 = g4;
        E = F; e4 = f4; e5 = f5;
        C = Cn; G = Gn; g4 = g4n; F = Fn; f4 = f4n; f5 = f5n;
        p += PS;
    }

    // wave (64-lane) shuffle reduce
    for (int off = 32; off > 0; off >>= 1)
        acc += __shfl_down(acc, off, 64);

    __shared__ float ws[TPB / 64];
    const int lane = threadIdx.x & 63;
    const int wv   = threadIdx.x >> 6;
    if (lane == 0) ws[wv] = acc;
    __syncthreads();
    if (threadIdx.x == 0) {
        float bsum = 0.f;
        #pragma unroll
        for (int i = 0; i < TPB / 64; ++i) bsum += ws[i];
        atomicAdd(out, bsum * (1.0f / (IH * IW)));
    }
}

extern "C" void kernel_launch(void* const* d_in, const int* in_sizes, int n_in,
                              void* d_out, int out_size, void* d_ws, size_t ws_size,
                              hipStream_t stream) {
    const float* img = (const float*)d_in[0];
    float* out = (float*)d_out;
    // d_out is re-poisoned to 0xAA before every timed launch -> zero it on-stream.
    hipMemsetAsync(out, 0, sizeof(float), stream);
    hipLaunchKernelGGL(HessianReg_kernel, dim3(BLOCKS), dim3(TPB), 0, stream, img, out);
}